// Round 8
// baseline (437.220 us; speedup 1.0000x reference)
//
#include <hip/hip_runtime.h>
#include <math.h>

#define KK 9
#define NB 4
#define NC 64
#define NO 64
#define NH 128
#define HP 136
#define NPIX (NH*NH)     /* 16384 */
#define PADPIX (HP*HP)   /* 18496 */
#define NCH 18

typedef short bf16x8 __attribute__((ext_vector_type(8)));
typedef float f32x4 __attribute__((ext_vector_type(4)));

/* workspace layout (float offsets) */
#define SZ_FP    (NB*NC*PADPIX)        /* 4,734,976 */
#define O_FPCHW  0
#define O_FPF16  (O_FPCHW + SZ_FP)              /* bf16 padded-flat: SZ_FP shorts */
#define SZ_FPF16F (SZ_FP/2)
#define O_OFF    (O_FPF16 + SZ_FPF16F)
#define SZ_OFF   (NB*NCH*NPIX)         /* 1,179,648 */
#define O_STATS  (O_OFF + SZ_OFF)
#define O_WXB    (O_STATS + 64)                 /* bf16 [k][o][c]: 36,864 shorts */
#define O_WYB    (O_WXB + KK*64*64/2)
#define O_R2     (O_WYB + KK*64*64/2)
#define SZ_R     (NB*KK*NPIX)          /* 589,824 */
#define O_R3     (O_R2 + SZ_R)
#define O_WR     (O_R3 + SZ_R)        /* fp32 repacked offset weights */
#define WS_FLOATS (O_WR + 64*1944)    /* ~9.62M floats = 38.5 MB */

/* k_prep block ranges */
#define NB_OFFZ  (SZ_OFF/1024)         /* 1152: zero `off` (float4) */
#define NB_BORD  256                   /* border-zero fpchw+fpf16 per (b,c) */
#define NB_PAD   1024                  /* pad tiles: 2 x 128 x 4 */
#define NB_WT    365                   /* weight repacks */
#define NB_PREP  (NB_OFFZ + NB_BORD + NB_PAD + NB_WT)

__device__ inline unsigned short f2bf(float x) {   /* RTNE fp32->bf16 */
    unsigned u = __float_as_uint(x);
    u += 0x7FFFu + ((u >> 16) & 1u);
    return (unsigned short)(u >> 16);
}

/* fused prep: zero `off` + zero pad borders + build padded layouts + repack
   weights. All regions disjoint -> no inter-block ordering needed. */
__global__ __launch_bounds__(256) void k_prep(const float* __restrict__ f,
                                              const float* __restrict__ cwx,
                                              const float* __restrict__ cwy,
                                              const float* __restrict__ offw,
                                              float* __restrict__ fpchw,
                                              unsigned short* __restrict__ fpf16,
                                              float* __restrict__ off,
                                              unsigned short* __restrict__ wxb,
                                              unsigned short* __restrict__ wyb,
                                              float* __restrict__ wr) {
    int blk = blockIdx.x;
    const int t = threadIdx.x;
    if (blk < NB_OFFZ) {                      /* zero off (for atomics) */
        ((float4*)off)[blk * 256 + t] = make_float4(0.f, 0.f, 0.f, 0.f);
        return;
    }
    blk -= NB_OFFZ;
    if (blk < NB_BORD) {                      /* zero pad borders */
        const int b = blk >> 6, c = blk & 63;
        float* pc = fpchw + (size_t)(b * 64 + c) * PADPIX;
        unsigned short* pf = fpf16 + (size_t)b * PADPIX * 64 + c;
        for (int e = t; e < 2112; e += 256) {
            int h, w;
            if (e < 544)       { h = e / 136;            w = e - h * 136; }
            else if (e < 1088) { int m = e - 544; h = 132 + m / 136; w = m - (h - 132) * 136; }
            else               { int m = e - 1088; h = 4 + (m >> 3);
                                 int ww = m & 7; w = (ww < 4) ? ww : 128 + ww; }
            pc[h * HP + w] = 0.f;
            pf[(size_t)(h * HP + w) * 64] = 0;
        }
        return;
    }
    blk -= NB_BORD;
    if (blk < NB_PAD) {                       /* padded layouts (interior) */
        __shared__ float tile[64][65];
        const int wt = blk & 1, h = (blk >> 1) & 127, b = blk >> 8;
        const int w0 = wt * 64;
        const int tc = t >> 6, tw = t & 63;
        for (int cc = tc; cc < 64; cc += 4) {
            float v = f[((b * 64 + cc) * 128 + h) * 128 + w0 + tw];
            tile[cc][tw] = v;
            fpchw[((b * 64 + cc) * HP + h + 4) * HP + w0 + tw + 4] = v;
        }
        __syncthreads();
        for (int pp = tc; pp < 64; pp += 4)
            fpf16[(((b * HP + h + 4) * HP) + w0 + pp + 4) * 64 + tw] =
                f2bf(tile[tw][pp]);
        return;
    }
    blk -= NB_PAD;
    {                                         /* weight repacks */
        int id = blk * 256 + t;
        if (id < KK * 64 * 64) {
            int o = (id >> 6) & 63;
            int c = id & 63;
            int k = id >> 12;
            wxb[id] = f2bf(cwx[(o * 64 + c) * 9 + k]);
            wyb[id] = f2bf(cwy[(o * 64 + c) * 9 + k]);
        }
        if (id < 18 * 64 * 9 * 9) {
            int kx = id % 9;
            int r = id / 9;
            int ky = r % 9; r /= 9;
            int c = r % 64;
            int co = r / 64;
            int cg = co / 6, u = co - cg * 6;   /* 6-wide co groups */
            wr[c * 1944 + cg * 648 + (ky * 6 + u) * 12 + kx] =
                offw[((co * 64 + c) * 9 + ky) * 9 + kx];
        }
    }
}

/* offset conv: NO LDS, 6 co x 4 j per thread, channel-EIGHTHS.
   Input via coalesced global dwordx4, weights via wave-uniform s_load.
   grid = (cg3*jt2, ig16, b4*eighth8) = 3072 blocks, 128 thr.
   Numerics: per-(co,c) fp32 tap chain ky->kx, double accumulation over
   ascending c within the eighth; eighths combined by fp32 atomicAdd
   (order-independent at ~2^-24 — proven harmless in r6/r7). */
__global__ __launch_bounds__(128) void k_off(const float* __restrict__ fpchw,
                                             const float* __restrict__ wr,
                                             float* __restrict__ off) {
    const int cg = blockIdx.x >> 1, jt = blockIdx.x & 1;   /* cg 0..2 */
    const int ig = blockIdx.y;                              /* 0..15 */
    const int b = blockIdx.z >> 3, eighth = blockIdx.z & 7;
    const int t = threadIdx.x;
    const int tr = t >> 4;            /* 0..7 */
    const int tjj = t & 15;
    const int i = ig * 8 + tr;        /* output row */
    const int j0 = jt * 64 + tjj * 4;
    const int c0 = eighth * 8, co0 = cg * 6;

    const float* frow0 = fpchw + ((size_t)(b * 64 + c0) * HP + i) * HP + j0;
    const float* wbase = wr + (size_t)c0 * 1944 + cg * 648;

    double acc[6][4];
#pragma unroll
    for (int u = 0; u < 6; ++u)
#pragma unroll
        for (int jj = 0; jj < 4; ++jj) acc[u][jj] = 0.0;

    for (int c = 0; c < 8; ++c) {
        const float* fr = frow0 + (size_t)c * PADPIX;
        const float* wc = wbase + (size_t)c * 1944;
        float p[6][4];
#pragma unroll
        for (int u = 0; u < 6; ++u)
#pragma unroll
            for (int jj = 0; jj < 4; ++jj) p[u][jj] = 0.f;
#pragma unroll
        for (int ky = 0; ky < 9; ++ky) {
            float4 va = *(const float4*)(fr + ky * HP);
            float4 vb = *(const float4*)(fr + ky * HP + 4);
            float4 vc = *(const float4*)(fr + ky * HP + 8);
            const float v[12] = {va.x, va.y, va.z, va.w, vb.x, vb.y, vb.z, vb.w,
                                 vc.x, vc.y, vc.z, vc.w};
#pragma unroll
            for (int u = 0; u < 6; ++u) {
                const float* wp = wc + (ky * 6 + u) * 12;   /* wave-uniform */
                float4 w0 = *(const float4*)(wp);
                float4 w1 = *(const float4*)(wp + 4);
                float w8 = wp[8];
                const float w[9] = {w0.x, w0.y, w0.z, w0.w,
                                    w1.x, w1.y, w1.z, w1.w, w8};
#pragma unroll
                for (int jj = 0; jj < 4; ++jj) {
                    float pu = p[u][jj];
#pragma unroll
                    for (int kx = 0; kx < 9; ++kx)
                        pu = fmaf(v[kx + jj], w[kx], pu);
                    p[u][jj] = pu;
                }
            }
        }
#pragma unroll
        for (int u = 0; u < 6; ++u)
#pragma unroll
            for (int jj = 0; jj < 4; ++jj) acc[u][jj] += (double)p[u][jj];
    }
#pragma unroll
    for (int u = 0; u < 6; ++u)
#pragma unroll
        for (int jj = 0; jj < 4; ++jj)
            atomicAdd(&off[((b * NCH + co0 + u) << 14) + (i << 7) + j0 + jj],
                      (float)acc[u][jj]);
}

/* per-channel mean / rsqrt(var+eps) in double — read-only (bias cancels in
   BN: (v+b) - mean(v+b) == v - mean(v); offset_b is zeros anyway). */
__global__ __launch_bounds__(256) void k_stats(const float* __restrict__ off,
                                               float* __restrict__ stats) {
    int ch = blockIdx.x, t = threadIdx.x;
    double s = 0.0, ss = 0.0;
    for (int p = t; p < NB * NPIX; p += 256) {
        int b = p >> 14, q = p & 16383;
        float v = off[((b * NCH + ch) << 14) + q];
        s += (double)v;
        ss += (double)v * (double)v;
    }
    __shared__ double sh1[256], sh2[256];
    sh1[t] = s; sh2[t] = ss;
    __syncthreads();
    for (int st = 128; st > 0; st >>= 1) {
        if (t < st) { sh1[t] += sh1[t + st]; sh2[t] += sh2[t + st]; }
        __syncthreads();
    }
    if (t == 0) {
        double n = (double)(NB * NPIX);
        double m = sh1[0] / n;
        double var = sh2[0] / n - m * m;
        stats[ch] = (float)m;
        stats[NCH + ch] = (float)(1.0 / sqrt(var + 1e-5));
    }
}

/* BN + tanh + cum + floor -> gather row indices (reproduces base-stride bug) */
__global__ __launch_bounds__(128) void k_idx(const float* __restrict__ off,
                                             const float* __restrict__ stats,
                                             const float* __restrict__ gamma,
                                             const float* __restrict__ beta,
                                             int* __restrict__ r2, int* __restrict__ r3) {
    int i = blockIdx.x, b = blockIdx.y, j = threadIdx.x;
    float tt[NCH];
#pragma unroll
    for (int ch = 0; ch < NCH; ++ch) {
        float v = off[((b * NCH + ch) << 14) + (i << 7) + j];
        v = (v - stats[ch]) * stats[NCH + ch];
        v = v * gamma[ch] + beta[ch];
        tt[ch] = (float)tanh((double)v);
    }
    float cz[9], cw[9];
    {
        const float* o = tt;
        cz[0] = 0.f;
        cz[1] = o[1];
        cz[2] = o[1] + o[2];
        cz[3] = (o[1] + o[2]) + o[3];
        cz[7] = o[7];
        cz[6] = o[7] + o[6];
        cz[5] = (o[7] + o[6]) + o[5];
        cz[4] = (cz[3] + cz[5]) * 0.5f;
        cz[8] = 0.f;
    }
    {
        const float* o = tt + 9;
        cw[0] = 0.f;
        cw[1] = o[1];
        cw[2] = o[1] + o[2];
        cw[3] = (o[1] + o[2]) + o[3];
        cw[7] = o[7];
        cw[6] = o[7] + o[6];
        cw[5] = (o[7] + o[6]) + o[5];
        cw[4] = (cw[3] + cw[5]) * 0.5f;
        cw[8] = 0.f;
    }
    const int rmax = NB * PADPIX - 1;
#pragma unroll
    for (int k = 0; k < 9; ++k) {
        int iy2 = (int)floorf((float)(i + 8 - k) + cz[k]);
        int ix2 = (int)floorf((float)(j + k) + cz[k]);
        int rr = b * 16384 + iy2 * HP + ix2;
        rr = rr < 0 ? 0 : (rr > rmax ? rmax : rr);
        r2[((b * 9 + k) << 14) + (i << 7) + j] = rr;
        int iy3 = (int)floorf((float)(i + k) + cw[k]);
        int ix3 = (int)floorf((float)(j + k) - cw[k]);
        int r3v = b * 16384 + iy3 * HP + ix3;
        r3v = r3v < 0 ? 0 : (r3v > rmax ? rmax : r3v);
        r3[((b * 9 + k) << 14) + (i << 7) + j] = r3v;
    }
}

/* main gathered strip-convs via MFMA bf16 16x16x32 (r7-proven). */
__global__ __launch_bounds__(256) void k_main(const unsigned short* __restrict__ fpf16,
                                              const int* __restrict__ r2,
                                              const int* __restrict__ r3,
                                              const unsigned short* __restrict__ wxb,
                                              const unsigned short* __restrict__ wyb,
                                              const float* __restrict__ bx,
                                              const float* __restrict__ by,
                                              float* __restrict__ out) {
    __shared__ __align__(16) unsigned char smem[2 * 64 * 72 * 2 > 64 * 68 * 4
                                                ? 2 * 64 * 72 * 2 : 64 * 68 * 4];
    unsigned short* sA = (unsigned short*)smem;            /* [64][72] */
    unsigned short* sW = (unsigned short*)smem + 64 * 72;  /* [64][72] */

    const int b = blockIdx.z, i = blockIdx.y, j0 = blockIdx.x * 64;
    const int t = threadIdx.x;
    const int wv = t >> 6, lane = t & 63;
    const int m = lane & 15, quad = lane >> 4;
    const int sj = t >> 2, q4 = t & 3;

    f32x4 acc[4];
#pragma unroll
    for (int ot = 0; ot < 4; ++ot) acc[ot] = (f32x4){0.f, 0.f, 0.f, 0.f};

    for (int q = 0; q < 18; ++q) {
        const int k = (q < 9) ? q : (q - 9);
        const int* rr = ((q < 9) ? r2 : r3) + (((b * 9 + k) << 14) + (i << 7) + j0);
        const unsigned short* wsrc = ((q < 9) ? wxb : wyb) + k * 4096;
        __syncthreads();
        {
            int row = rr[sj];
            const uint4* src = (const uint4*)(fpf16 + (size_t)row * 64 + q4 * 16);
            uint4 v0 = src[0], v1 = src[1];
            *(uint4*)(sA + sj * 72 + q4 * 16) = v0;
            *(uint4*)(sA + sj * 72 + q4 * 16 + 8) = v1;
            const uint4* wsp = (const uint4*)(wsrc + sj * 64 + q4 * 16);
            uint4 w0 = wsp[0], w1 = wsp[1];
            *(uint4*)(sW + sj * 72 + q4 * 16) = w0;
            *(uint4*)(sW + sj * 72 + q4 * 16 + 8) = w1;
        }
        __syncthreads();
        bf16x8 a0 = *(const bf16x8*)(sA + (wv * 16 + m) * 72 + quad * 8);
        bf16x8 a1 = *(const bf16x8*)(sA + (wv * 16 + m) * 72 + 32 + quad * 8);
#pragma unroll
        for (int ot = 0; ot < 4; ++ot) {
            bf16x8 b0 = *(const bf16x8*)(sW + (ot * 16 + m) * 72 + quad * 8);
            bf16x8 b1 = *(const bf16x8*)(sW + (ot * 16 + m) * 72 + 32 + quad * 8);
            acc[ot] = __builtin_amdgcn_mfma_f32_16x16x32_bf16(a0, b0, acc[ot], 0, 0, 0);
            acc[ot] = __builtin_amdgcn_mfma_f32_16x16x32_bf16(a1, b1, acc[ot], 0, 0, 0);
        }
    }
    __syncthreads();
    float* sD = (float*)smem;
#pragma unroll
    for (int ot = 0; ot < 4; ++ot) {
        int o = ot * 16 + m;
        int jr = wv * 16 + quad * 4;
#pragma unroll
        for (int r = 0; r < 4; ++r)
            sD[o * 68 + jr + r] = acc[ot][r];
    }
    __syncthreads();
    {
        int o = t >> 2, jq = t & 3;
        float bias = bx[o] + by[o];
        float* dst = out + (((b * NO + o) << 7) + i) * NH + j0 + jq * 16;
        const float* srcrow = sD + o * 68 + jq * 16;
#pragma unroll
        for (int u = 0; u < 4; ++u) {
            float4 v = *(const float4*)(srcrow + u * 4);
            v.x += bias; v.y += bias; v.z += bias; v.w += bias;
            *(float4*)(dst + u * 4) = v;
        }
    }
}

extern "C" void kernel_launch(void* const* d_in, const int* in_sizes, int n_in,
                              void* d_out, int out_size, void* d_ws, size_t ws_size,
                              hipStream_t stream) {
    const float* f     = (const float*)d_in[0];
    const float* offw  = (const float*)d_in[1];
    const float* gamma = (const float*)d_in[3];
    const float* beta  = (const float*)d_in[4];
    const float* cwx   = (const float*)d_in[5];
    const float* cbx   = (const float*)d_in[6];
    const float* cwy   = (const float*)d_in[7];
    const float* cby   = (const float*)d_in[8];
    float* ws = (float*)d_ws;
    float* fpchw  = ws + O_FPCHW;
    unsigned short* fpf16 = (unsigned short*)(ws + O_FPF16);
    float* off    = ws + O_OFF;
    float* stats  = ws + O_STATS;
    unsigned short* wxb = (unsigned short*)(ws + O_WXB);
    unsigned short* wyb = (unsigned short*)(ws + O_WYB);
    float* wr     = ws + O_WR;
    int*   r2     = (int*)(ws + O_R2);
    int*   r3     = (int*)(ws + O_R3);
    float* out    = (float*)d_out;

    k_prep<<<NB_PREP, 256, 0, stream>>>(f, cwx, cwy, offw, fpchw, fpf16, off,
                                        wxb, wyb, wr);
    k_off<<<dim3(6, 16, NB * 8), 128, 0, stream>>>(fpchw, wr, off);
    k_stats<<<NCH, 256, 0, stream>>>(off, stats);
    k_idx<<<dim3(NH, NB), 128, 0, stream>>>(off, stats, gamma, beta, r2, r3);
    k_main<<<dim3(2, NH, NB), 256, 0, stream>>>(fpf16, r2, r3, wxb, wyb, cbx, cby, out);
}

// Round 9
// 287.525 us; speedup vs baseline: 1.5206x; 1.5206x over previous
//
#include <hip/hip_runtime.h>
#include <math.h>

#define KK 9
#define NB 4
#define NC 64
#define NO 64
#define NH 128
#define HP 136
#define NPIX (NH*NH)     /* 16384 */
#define PADPIX (HP*HP)   /* 18496 */
#define NCH 18

typedef short bf16x8 __attribute__((ext_vector_type(8)));
typedef float f32x4 __attribute__((ext_vector_type(4)));

/* workspace layout (float offsets) */
#define SZ_FP    (NB*NC*PADPIX)        /* 4,734,976 */
#define O_FPCHW  0
#define O_FPF16  (O_FPCHW + SZ_FP)               /* bf16 padded-flat (shorts) */
#define SZ_FPF16F (SZ_FP/2)
#define O_OFF    (O_FPF16 + SZ_FPF16F)           /* quarter-0 partial + combined */
#define SZ_OFF   (NB*NCH*NPIX)         /* 1,179,648 */
#define O_STATS  (O_OFF + SZ_OFF)                /* 64 floats */
#define O_PST    (O_STATS + 64)                  /* 288 doubles = 576 fl (pad 640) */
#define O_WXB    (O_PST + 640)                   /* bf16 [k][o][c]: 36,864 shorts */
#define O_WYB    (O_WXB + KK*64*64/2)
#define O_R2     (O_WYB + KK*64*64/2)
#define SZ_R     (NB*KK*NPIX)          /* 589,824 */
#define O_R3     (O_R2 + SZ_R)
/* quarter-1 partial overlays r2+r3 (dead until k_idx writes them) */
#define O_PP1    O_R2
#define O_WR     (O_R3 + SZ_R)        /* fp32 repacked offset weights */
#define O_PP2    (O_WR + 64*1944)
#define O_PP3    (O_PP2 + SZ_OFF)
#define WS_FLOATS (O_PP3 + SZ_OFF)    /* 11,983,040 floats = 47.9 MB */

/* k_prep block ranges */
#define NB_BORD  256                   /* border-zero fpchw+fpf16 per (b,c) */
#define NB_PAD   1024                  /* pad tiles: 2 x 128 x 4 */
#define NB_WT    365                   /* weight repacks */
#define NB_PREP  (NB_BORD + NB_PAD + NB_WT)

__device__ inline unsigned short f2bf(float x) {   /* RTNE fp32->bf16 */
    unsigned u = __float_as_uint(x);
    u += 0x7FFFu + ((u >> 16) & 1u);
    return (unsigned short)(u >> 16);
}

/* fused prep: zero pad borders + build padded layouts + repack weights. */
__global__ __launch_bounds__(256) void k_prep(const float* __restrict__ f,
                                              const float* __restrict__ cwx,
                                              const float* __restrict__ cwy,
                                              const float* __restrict__ offw,
                                              float* __restrict__ fpchw,
                                              unsigned short* __restrict__ fpf16,
                                              unsigned short* __restrict__ wxb,
                                              unsigned short* __restrict__ wyb,
                                              float* __restrict__ wr) {
    int blk = blockIdx.x;
    const int t = threadIdx.x;
    if (blk < NB_BORD) {                      /* zero pad borders */
        const int b = blk >> 6, c = blk & 63;
        float* pc = fpchw + (size_t)(b * 64 + c) * PADPIX;
        unsigned short* pf = fpf16 + (size_t)b * PADPIX * 64 + c;
        for (int e = t; e < 2112; e += 256) {
            int h, w;
            if (e < 544)       { h = e / 136;            w = e - h * 136; }
            else if (e < 1088) { int m = e - 544; h = 132 + m / 136; w = m - (h - 132) * 136; }
            else               { int m = e - 1088; h = 4 + (m >> 3);
                                 int ww = m & 7; w = (ww < 4) ? ww : 128 + ww; }
            pc[h * HP + w] = 0.f;
            pf[(size_t)(h * HP + w) * 64] = 0;
        }
        return;
    }
    blk -= NB_BORD;
    if (blk < NB_PAD) {                       /* padded layouts (interior) */
        __shared__ float tile[64][65];
        const int wt = blk & 1, h = (blk >> 1) & 127, b = blk >> 8;
        const int w0 = wt * 64;
        const int tc = t >> 6, tw = t & 63;
        for (int cc = tc; cc < 64; cc += 4) {
            float v = f[((b * 64 + cc) * 128 + h) * 128 + w0 + tw];
            tile[cc][tw] = v;
            fpchw[((b * 64 + cc) * HP + h + 4) * HP + w0 + tw + 4] = v;
        }
        __syncthreads();
        for (int pp = tc; pp < 64; pp += 4)
            fpf16[(((b * HP + h + 4) * HP) + w0 + pp + 4) * 64 + tw] =
                f2bf(tile[tw][pp]);
        return;
    }
    blk -= NB_PAD;
    {                                         /* weight repacks */
        int id = blk * 256 + t;
        if (id < KK * 64 * 64) {
            int o = (id >> 6) & 63;
            int c = id & 63;
            int k = id >> 12;
            wxb[id] = f2bf(cwx[(o * 64 + c) * 9 + k]);
            wyb[id] = f2bf(cwy[(o * 64 + c) * 9 + k]);
        }
        if (id < 18 * 64 * 9 * 9) {
            int kx = id % 9;
            int r = id / 9;
            int ky = r % 9; r /= 9;
            int c = r % 64;
            int co = r / 64;
            int cg = co / 3, u = co - cg * 3;   /* 3-wide co groups (r6) */
            wr[c * 1944 + cg * 324 + (ky * 3 + u) * 12 + kx] =
                offw[((co * 64 + c) * 9 + ky) * 9 + kx];
        }
    }
}

/* offset conv: NO LDS, 3 co x 4 j per thread, channel quarters, one-row-ahead
   prefetch, plain coalesced stores to per-quarter buffers (no atomics).
   grid = (cg6*jt2, ig16, b4*quarter4) = 3072 blocks, 128 thr, 6 waves/SIMD.
   Numerics: per-(co,c) fp32 tap chain ky->kx, double accumulation over
   ascending c within the quarter (bit-identical to r6's per-quarter math). */
__global__ __launch_bounds__(128, 6) void k_off(const float* __restrict__ fpchw,
                                                const float* __restrict__ wr,
                                                float* __restrict__ q0,
                                                float* __restrict__ q1,
                                                float* __restrict__ q2,
                                                float* __restrict__ q3) {
    const int cg = blockIdx.x >> 1, jt = blockIdx.x & 1;   /* cg 0..5 */
    const int ig = blockIdx.y;                              /* 0..15 */
    const int b = blockIdx.z >> 2, quarter = blockIdx.z & 3;
    const int t = threadIdx.x;
    const int tr = t >> 4;            /* 0..7 */
    const int tjj = t & 15;
    const int i = ig * 8 + tr;        /* output row */
    const int j0 = jt * 64 + tjj * 4;
    const int c0 = quarter * 16, co0 = cg * 3;
    float* pout = (quarter == 0) ? q0 : (quarter == 1) ? q1
                : (quarter == 2) ? q2 : q3;

    const float* frow0 = fpchw + ((size_t)(b * 64 + c0) * HP + i) * HP + j0;
    const float* wbase = wr + (size_t)c0 * 1944 + cg * 324;

    double acc[3][4];
#pragma unroll
    for (int u = 0; u < 3; ++u)
#pragma unroll
        for (int jj = 0; jj < 4; ++jj) acc[u][jj] = 0.0;

    float4 cva = *(const float4*)(frow0);
    float4 cvb = *(const float4*)(frow0 + 4);
    float4 cvc = *(const float4*)(frow0 + 8);

    for (int c = 0; c < 16; ++c) {
        const float* fr = frow0 + (size_t)c * PADPIX;
        const float* wc = wbase + (size_t)c * 1944;
        float p[3][4];
#pragma unroll
        for (int u = 0; u < 3; ++u)
#pragma unroll
            for (int jj = 0; jj < 4; ++jj) p[u][jj] = 0.f;
#pragma unroll
        for (int ky = 0; ky < 9; ++ky) {
            /* prefetch next row (ky+1, or first row of c+1); at the very
               last iteration this reads one channel past — still inside ws */
            const float* nf = (ky < 8) ? (fr + (ky + 1) * HP) : (fr + PADPIX);
            float4 nva = *(const float4*)(nf);
            float4 nvb = *(const float4*)(nf + 4);
            float4 nvc = *(const float4*)(nf + 8);
            const float v[12] = {cva.x, cva.y, cva.z, cva.w,
                                 cvb.x, cvb.y, cvb.z, cvb.w,
                                 cvc.x, cvc.y, cvc.z, cvc.w};
#pragma unroll
            for (int u = 0; u < 3; ++u) {
                const float* wp = wc + (ky * 3 + u) * 12;   /* wave-uniform */
                float4 w0 = *(const float4*)(wp);
                float4 w1 = *(const float4*)(wp + 4);
                float w8 = wp[8];
                const float w[9] = {w0.x, w0.y, w0.z, w0.w,
                                    w1.x, w1.y, w1.z, w1.w, w8};
#pragma unroll
                for (int jj = 0; jj < 4; ++jj) {
                    float pu = p[u][jj];
#pragma unroll
                    for (int kx = 0; kx < 9; ++kx)
                        pu = fmaf(v[kx + jj], w[kx], pu);
                    p[u][jj] = pu;
                }
            }
            cva = nva; cvb = nvb; cvc = nvc;
        }
#pragma unroll
        for (int u = 0; u < 3; ++u)
#pragma unroll
            for (int jj = 0; jj < 4; ++jj) acc[u][jj] += (double)p[u][jj];
    }
#pragma unroll
    for (int u = 0; u < 3; ++u) {
        float4 o4 = make_float4((float)acc[u][0], (float)acc[u][1],
                                (float)acc[u][2], (float)acc[u][3]);
        *(float4*)&pout[((b * NCH + co0 + u) << 14) + (i << 7) + j0] = o4;
    }
}

/* combine quarters (deterministic order) -> off, plus per-(ch,part) partial
   double sums for the BN stats. grid (18, 8). */
__global__ __launch_bounds__(256) void k_stats1(float* __restrict__ qoff,
                                                const float* __restrict__ q1,
                                                const float* __restrict__ q2,
                                                const float* __restrict__ q3,
                                                double* __restrict__ pstat) {
    const int ch = blockIdx.x, part = blockIdx.y, t = threadIdx.x;
    double s = 0.0, ss = 0.0;
    const int pend = (part + 1) * 8192;
    for (int p = part * 8192 + t; p < pend; p += 256) {
        int b = p >> 14, q = p & 16383;
        int x = ((b * NCH + ch) << 14) + q;
        float v = ((qoff[x] + q1[x]) + q2[x]) + q3[x];
        qoff[x] = v;
        s += (double)v;
        ss += (double)v * (double)v;
    }
    __shared__ double sh1[256], sh2[256];
    sh1[t] = s; sh2[t] = ss;
    __syncthreads();
    for (int st = 128; st > 0; st >>= 1) {
        if (t < st) { sh1[t] += sh1[t + st]; sh2[t] += sh2[t + st]; }
        __syncthreads();
    }
    if (t == 0) {
        pstat[(ch * 8 + part) * 2] = sh1[0];
        pstat[(ch * 8 + part) * 2 + 1] = sh2[0];
    }
}

/* finish stats: mean / rsqrt(var+eps) per channel */
__global__ void k_stats2(const double* __restrict__ pstat,
                         float* __restrict__ stats) {
    int t = threadIdx.x;
    if (t < NCH) {
        double s = 0.0, ss = 0.0;
        for (int k = 0; k < 8; ++k) {
            s += pstat[(t * 8 + k) * 2];
            ss += pstat[(t * 8 + k) * 2 + 1];
        }
        double n = (double)(NB * NPIX);
        double m = s / n;
        double var = ss / n - m * m;
        stats[t] = (float)m;
        stats[NCH + t] = (float)(1.0 / sqrt(var + 1e-5));
    }
}

/* BN + tanh + cum + floor -> gather row indices (reproduces base-stride bug) */
__global__ __launch_bounds__(128) void k_idx(const float* __restrict__ off,
                                             const float* __restrict__ stats,
                                             const float* __restrict__ gamma,
                                             const float* __restrict__ beta,
                                             int* __restrict__ r2, int* __restrict__ r3) {
    int i = blockIdx.x, b = blockIdx.y, j = threadIdx.x;
    float tt[NCH];
#pragma unroll
    for (int ch = 0; ch < NCH; ++ch) {
        float v = off[((b * NCH + ch) << 14) + (i << 7) + j];
        v = (v - stats[ch]) * stats[NCH + ch];
        v = v * gamma[ch] + beta[ch];
        tt[ch] = (float)tanh((double)v);
    }
    float cz[9], cw[9];
    {
        const float* o = tt;
        cz[0] = 0.f;
        cz[1] = o[1];
        cz[2] = o[1] + o[2];
        cz[3] = (o[1] + o[2]) + o[3];
        cz[7] = o[7];
        cz[6] = o[7] + o[6];
        cz[5] = (o[7] + o[6]) + o[5];
        cz[4] = (cz[3] + cz[5]) * 0.5f;
        cz[8] = 0.f;
    }
    {
        const float* o = tt + 9;
        cw[0] = 0.f;
        cw[1] = o[1];
        cw[2] = o[1] + o[2];
        cw[3] = (o[1] + o[2]) + o[3];
        cw[7] = o[7];
        cw[6] = o[7] + o[6];
        cw[5] = (o[7] + o[6]) + o[5];
        cw[4] = (cw[3] + cw[5]) * 0.5f;
        cw[8] = 0.f;
    }
    const int rmax = NB * PADPIX - 1;
#pragma unroll
    for (int k = 0; k < 9; ++k) {
        int iy2 = (int)floorf((float)(i + 8 - k) + cz[k]);
        int ix2 = (int)floorf((float)(j + k) + cz[k]);
        int rr = b * 16384 + iy2 * HP + ix2;
        rr = rr < 0 ? 0 : (rr > rmax ? rmax : rr);
        r2[((b * 9 + k) << 14) + (i << 7) + j] = rr;
        int iy3 = (int)floorf((float)(i + k) + cw[k]);
        int ix3 = (int)floorf((float)(j + k) - cw[k]);
        int r3v = b * 16384 + iy3 * HP + ix3;
        r3v = r3v < 0 ? 0 : (r3v > rmax ? rmax : r3v);
        r3[((b * 9 + k) << 14) + (i << 7) + j] = r3v;
    }
}

/* main gathered strip-convs via MFMA bf16 16x16x32 (r7-proven). */
__global__ __launch_bounds__(256) void k_main(const unsigned short* __restrict__ fpf16,
                                              const int* __restrict__ r2,
                                              const int* __restrict__ r3,
                                              const unsigned short* __restrict__ wxb,
                                              const unsigned short* __restrict__ wyb,
                                              const float* __restrict__ bx,
                                              const float* __restrict__ by,
                                              float* __restrict__ out) {
    __shared__ __align__(16) unsigned char smem[2 * 64 * 72 * 2 > 64 * 68 * 4
                                                ? 2 * 64 * 72 * 2 : 64 * 68 * 4];
    unsigned short* sA = (unsigned short*)smem;            /* [64][72] */
    unsigned short* sW = (unsigned short*)smem + 64 * 72;  /* [64][72] */

    const int b = blockIdx.z, i = blockIdx.y, j0 = blockIdx.x * 64;
    const int t = threadIdx.x;
    const int wv = t >> 6, lane = t & 63;
    const int m = lane & 15, quad = lane >> 4;
    const int sj = t >> 2, q4 = t & 3;

    f32x4 acc[4];
#pragma unroll
    for (int ot = 0; ot < 4; ++ot) acc[ot] = (f32x4){0.f, 0.f, 0.f, 0.f};

    for (int q = 0; q < 18; ++q) {
        const int k = (q < 9) ? q : (q - 9);
        const int* rr = ((q < 9) ? r2 : r3) + (((b * 9 + k) << 14) + (i << 7) + j0);
        const unsigned short* wsrc = ((q < 9) ? wxb : wyb) + k * 4096;
        __syncthreads();
        {
            int row = rr[sj];
            const uint4* src = (const uint4*)(fpf16 + (size_t)row * 64 + q4 * 16);
            uint4 v0 = src[0], v1 = src[1];
            *(uint4*)(sA + sj * 72 + q4 * 16) = v0;
            *(uint4*)(sA + sj * 72 + q4 * 16 + 8) = v1;
            const uint4* wsp = (const uint4*)(wsrc + sj * 64 + q4 * 16);
            uint4 w0 = wsp[0], w1 = wsp[1];
            *(uint4*)(sW + sj * 72 + q4 * 16) = w0;
            *(uint4*)(sW + sj * 72 + q4 * 16 + 8) = w1;
        }
        __syncthreads();
        bf16x8 a0 = *(const bf16x8*)(sA + (wv * 16 + m) * 72 + quad * 8);
        bf16x8 a1 = *(const bf16x8*)(sA + (wv * 16 + m) * 72 + 32 + quad * 8);
#pragma unroll
        for (int ot = 0; ot < 4; ++ot) {
            bf16x8 b0 = *(const bf16x8*)(sW + (ot * 16 + m) * 72 + quad * 8);
            bf16x8 b1 = *(const bf16x8*)(sW + (ot * 16 + m) * 72 + 32 + quad * 8);
            acc[ot] = __builtin_amdgcn_mfma_f32_16x16x32_bf16(a0, b0, acc[ot], 0, 0, 0);
            acc[ot] = __builtin_amdgcn_mfma_f32_16x16x32_bf16(a1, b1, acc[ot], 0, 0, 0);
        }
    }
    __syncthreads();
    float* sD = (float*)smem;
#pragma unroll
    for (int ot = 0; ot < 4; ++ot) {
        int o = ot * 16 + m;
        int jr = wv * 16 + quad * 4;
#pragma unroll
        for (int r = 0; r < 4; ++r)
            sD[o * 68 + jr + r] = acc[ot][r];
    }
    __syncthreads();
    {
        int o = t >> 2, jq = t & 3;
        float bias = bx[o] + by[o];
        float* dst = out + (((b * NO + o) << 7) + i) * NH + j0 + jq * 16;
        const float* srcrow = sD + o * 68 + jq * 16;
#pragma unroll
        for (int u = 0; u < 4; ++u) {
            float4 v = *(const float4*)(srcrow + u * 4);
            v.x += bias; v.y += bias; v.z += bias; v.w += bias;
            *(float4*)(dst + u * 4) = v;
        }
    }
}

extern "C" void kernel_launch(void* const* d_in, const int* in_sizes, int n_in,
                              void* d_out, int out_size, void* d_ws, size_t ws_size,
                              hipStream_t stream) {
    const float* f     = (const float*)d_in[0];
    const float* offw  = (const float*)d_in[1];
    const float* gamma = (const float*)d_in[3];
    const float* beta  = (const float*)d_in[4];
    const float* cwx   = (const float*)d_in[5];
    const float* cbx   = (const float*)d_in[6];
    const float* cwy   = (const float*)d_in[7];
    const float* cby   = (const float*)d_in[8];
    float* ws = (float*)d_ws;
    float* fpchw  = ws + O_FPCHW;
    unsigned short* fpf16 = (unsigned short*)(ws + O_FPF16);
    float* off    = ws + O_OFF;      /* quarter-0 partial, then combined */
    float* stats  = ws + O_STATS;
    double* pstat = (double*)(ws + O_PST);
    unsigned short* wxb = (unsigned short*)(ws + O_WXB);
    unsigned short* wyb = (unsigned short*)(ws + O_WYB);
    float* pp1    = ws + O_PP1;      /* overlays r2+r3 (dead until k_idx) */
    float* pp2    = ws + O_PP2;
    float* pp3    = ws + O_PP3;
    float* wr     = ws + O_WR;
    int*   r2     = (int*)(ws + O_R2);
    int*   r3     = (int*)(ws + O_R3);
    float* out    = (float*)d_out;

    k_prep<<<NB_PREP, 256, 0, stream>>>(f, cwx, cwy, offw, fpchw, fpf16,
                                        wxb, wyb, wr);
    k_off<<<dim3(12, 16, NB * 4), 128, 0, stream>>>(fpchw, wr, off, pp1, pp2, pp3);
    k_stats1<<<dim3(NCH, 8), 256, 0, stream>>>(off, pp1, pp2, pp3, pstat);
    k_stats2<<<1, 64, 0, stream>>>(pstat, stats);
    k_idx<<<dim3(NH, NB), 128, 0, stream>>>(off, stats, gamma, beta, r2, r3);
    k_main<<<dim3(2, NH, NB), 256, 0, stream>>>(fpf16, r2, r3, wxb, wyb, cbx, cby, out);
}

// Round 10
// 279.772 us; speedup vs baseline: 1.5628x; 1.0277x over previous
//
#include <hip/hip_runtime.h>
#include <math.h>

#define KK 9
#define NB 4
#define NC 64
#define NO 64
#define NH 128
#define HP 136
#define NPIX (NH*NH)     /* 16384 */
#define PADPIX (HP*HP)   /* 18496 */
#define NCH 18

typedef short bf16x8 __attribute__((ext_vector_type(8)));
typedef float f32x4 __attribute__((ext_vector_type(4)));

/* workspace layout (float offsets) */
#define SZ_FP    (NB*NC*PADPIX)        /* 4,734,976 */
#define O_FPCHW  0
#define O_FPF16  (O_FPCHW + SZ_FP)               /* bf16 padded-flat (shorts) */
#define SZ_FPF16F (SZ_FP/2)
#define O_OFF    (O_FPF16 + SZ_FPF16F)           /* quarter-0 partial + combined */
#define SZ_OFF   (NB*NCH*NPIX)         /* 1,179,648 */
#define O_STATS  (O_OFF + SZ_OFF)                /* 64 floats (unused spare) */
#define O_PST    (O_STATS + 64)                  /* 288 doubles (pad 640 fl) */
#define O_WXB    (O_PST + 640)                   /* bf16 [k][o][c]: 36,864 shorts */
#define O_WYB    (O_WXB + KK*64*64/2)
#define O_R2     (O_WYB + KK*64*64/2)
#define SZ_R     (NB*KK*NPIX)          /* 589,824 */
#define O_R3     (O_R2 + SZ_R)
/* quarter-1 partial overlays r2+r3 (dead until k_idx writes them) */
#define O_PP1    O_R2
#define O_WR     (O_R3 + SZ_R)        /* fp32 repacked offset weights */
#define O_PP2    (O_WR + 64*1944)
#define O_PP3    (O_PP2 + SZ_OFF)
#define WS_FLOATS (O_PP3 + SZ_OFF)    /* 11,983,040 floats = 47.9 MB */

/* k_prep block ranges */
#define NB_BORD  256                   /* border-zero fpchw per (b,c) */
#define NB_B16   16                    /* border-zero fpf16, contiguous per pixel */
#define NB_PAD   1024                  /* pad tiles: 2 x 128 x 4 */
#define NB_WT    365                   /* weight repacks */
#define NB_PREP  (NB_BORD + NB_B16 + NB_PAD + NB_WT)

__device__ inline unsigned short f2bf(float x) {   /* RTNE fp32->bf16 */
    unsigned u = __float_as_uint(x);
    u += 0x7FFFu + ((u >> 16) & 1u);
    return (unsigned short)(u >> 16);
}

__device__ inline void border_hw(int e, int* h, int* w) {
    if (e < 544)       { *h = e / 136; *w = e - *h * 136; }
    else if (e < 1088) { int m = e - 544; *h = 132 + m / 136; *w = m - (*h - 132) * 136; }
    else               { int m = e - 1088; *h = 4 + (m >> 3);
                         int ww = m & 7; *w = (ww < 4) ? ww : 128 + ww; }
}

/* fused prep: zero pad borders + build padded layouts + repack weights. */
__global__ __launch_bounds__(256) void k_prep(const float* __restrict__ f,
                                              const float* __restrict__ cwx,
                                              const float* __restrict__ cwy,
                                              const float* __restrict__ offw,
                                              float* __restrict__ fpchw,
                                              unsigned short* __restrict__ fpf16,
                                              unsigned short* __restrict__ wxb,
                                              unsigned short* __restrict__ wyb,
                                              float* __restrict__ wr) {
    int blk = blockIdx.x;
    const int t = threadIdx.x;
    if (blk < NB_BORD) {                      /* zero fpchw borders */
        const int b = blk >> 6, c = blk & 63;
        float* pc = fpchw + (size_t)(b * 64 + c) * PADPIX;
        for (int e = t; e < 2112; e += 256) {
            int h, w; border_hw(e, &h, &w);
            pc[h * HP + w] = 0.f;
        }
        return;
    }
    blk -= NB_BORD;
    if (blk < NB_B16) {                       /* zero fpf16 borders, 128B/pixel */
        const int b = blk >> 2, seg = blk & 3;
        unsigned short* pf = fpf16 + (size_t)b * PADPIX * 64;
        for (int u = t; u < 4224; u += 256) {  /* 528 pixels x 8 uint4 */
            int pix = seg * 528 + (u >> 3), part = u & 7;
            int h, w; border_hw(pix, &h, &w);
            *(uint4*)(pf + (size_t)(h * HP + w) * 64 + part * 8) =
                make_uint4(0u, 0u, 0u, 0u);
        }
        return;
    }
    blk -= NB_B16;
    if (blk < NB_PAD) {                       /* padded layouts (interior) */
        __shared__ float tile[64][65];
        const int wt = blk & 1, h = (blk >> 1) & 127, b = blk >> 8;
        const int w0 = wt * 64;
        const int tc = t >> 6, tw = t & 63;
        for (int cc = tc; cc < 64; cc += 4) {
            float v = f[((b * 64 + cc) * 128 + h) * 128 + w0 + tw];
            tile[cc][tw] = v;
            fpchw[((b * 64 + cc) * HP + h + 4) * HP + w0 + tw + 4] = v;
        }
        __syncthreads();
        for (int pp = tc; pp < 64; pp += 4)
            fpf16[(((b * HP + h + 4) * HP) + w0 + pp + 4) * 64 + tw] =
                f2bf(tile[tw][pp]);
        return;
    }
    blk -= NB_PAD;
    {                                         /* weight repacks */
        int id = blk * 256 + t;
        if (id < KK * 64 * 64) {
            int o = (id >> 6) & 63;
            int c = id & 63;
            int k = id >> 12;
            wxb[id] = f2bf(cwx[(o * 64 + c) * 9 + k]);
            wyb[id] = f2bf(cwy[(o * 64 + c) * 9 + k]);
        }
        if (id < 18 * 64 * 9 * 9) {
            int kx = id % 9;
            int r = id / 9;
            int ky = r % 9; r /= 9;
            int c = r % 64;
            int co = r / 64;
            int cg = co / 3, u = co - cg * 3;
            wr[c * 1944 + cg * 324 + (ky * 3 + u) * 12 + kx] =
                offw[((co * 64 + c) * 9 + ky) * 9 + kx];
        }
    }
}

/* offset conv (r9 math, XCD-swizzled): flat grid 3072; slab (b,quarter) in the
   low 4 bits so all 192 blocks sharing a 1.2MB channel-slab land on the same
   XCD (id%8 striping heuristic) -> slab stays resident in that XCD's L2.
   3 co x 4 j per thread, one-row-ahead prefetch, per-quarter output buffers.
   Numerics bit-identical to r9. */
__global__ __launch_bounds__(128, 6) void k_off(const float* __restrict__ fpchw,
                                                const float* __restrict__ wr,
                                                float* __restrict__ q0,
                                                float* __restrict__ q1,
                                                float* __restrict__ q2,
                                                float* __restrict__ q3) {
    const int id = blockIdx.x;
    const int slab = id & 15;                  /* b*4 + quarter */
    const int b = slab >> 2, quarter = slab & 3;
    const int rest = id >> 4;                  /* cg*32 + ig*2 + jt */
    const int cg = rest >> 5;
    const int ig = (rest >> 1) & 15;
    const int jt = rest & 1;
    const int t = threadIdx.x;
    const int tr = t >> 4;
    const int tjj = t & 15;
    const int i = ig * 8 + tr;
    const int j0 = jt * 64 + tjj * 4;
    const int c0 = quarter * 16, co0 = cg * 3;
    float* pout = (quarter == 0) ? q0 : (quarter == 1) ? q1
                : (quarter == 2) ? q2 : q3;

    const float* frow0 = fpchw + ((size_t)(b * 64 + c0) * HP + i) * HP + j0;
    const float* wbase = wr + (size_t)c0 * 1944 + cg * 324;

    double acc[3][4];
#pragma unroll
    for (int u = 0; u < 3; ++u)
#pragma unroll
        for (int jj = 0; jj < 4; ++jj) acc[u][jj] = 0.0;

    float4 cva = *(const float4*)(frow0);
    float4 cvb = *(const float4*)(frow0 + 4);
    float4 cvc = *(const float4*)(frow0 + 8);

    for (int c = 0; c < 16; ++c) {
        const float* fr = frow0 + (size_t)c * PADPIX;
        const float* wc = wbase + (size_t)c * 1944;
        float p[3][4];
#pragma unroll
        for (int u = 0; u < 3; ++u)
#pragma unroll
            for (int jj = 0; jj < 4; ++jj) p[u][jj] = 0.f;
#pragma unroll
        for (int ky = 0; ky < 9; ++ky) {
            const float* nf = (ky < 8) ? (fr + (ky + 1) * HP) : (fr + PADPIX);
            float4 nva = *(const float4*)(nf);
            float4 nvb = *(const float4*)(nf + 4);
            float4 nvc = *(const float4*)(nf + 8);
            const float v[12] = {cva.x, cva.y, cva.z, cva.w,
                                 cvb.x, cvb.y, cvb.z, cvb.w,
                                 cvc.x, cvc.y, cvc.z, cvc.w};
#pragma unroll
            for (int u = 0; u < 3; ++u) {
                const float* wp = wc + (ky * 3 + u) * 12;   /* wave-uniform */
                float4 w0 = *(const float4*)(wp);
                float4 w1 = *(const float4*)(wp + 4);
                float w8 = wp[8];
                const float w[9] = {w0.x, w0.y, w0.z, w0.w,
                                    w1.x, w1.y, w1.z, w1.w, w8};
#pragma unroll
                for (int jj = 0; jj < 4; ++jj) {
                    float pu = p[u][jj];
#pragma unroll
                    for (int kx = 0; kx < 9; ++kx)
                        pu = fmaf(v[kx + jj], w[kx], pu);
                    p[u][jj] = pu;
                }
            }
            cva = nva; cvb = nvb; cvc = nvc;
        }
#pragma unroll
        for (int u = 0; u < 3; ++u)
#pragma unroll
            for (int jj = 0; jj < 4; ++jj) acc[u][jj] += (double)p[u][jj];
    }
#pragma unroll
    for (int u = 0; u < 3; ++u) {
        float4 o4 = make_float4((float)acc[u][0], (float)acc[u][1],
                                (float)acc[u][2], (float)acc[u][3]);
        *(float4*)&pout[((b * NCH + co0 + u) << 14) + (i << 7) + j0] = o4;
    }
}

/* combine quarters (deterministic order) -> off + per-(ch,part) partial sums */
__global__ __launch_bounds__(256) void k_stats1(float* __restrict__ qoff,
                                                const float* __restrict__ q1,
                                                const float* __restrict__ q2,
                                                const float* __restrict__ q3,
                                                double* __restrict__ pstat) {
    const int ch = blockIdx.x, part = blockIdx.y, t = threadIdx.x;
    double s = 0.0, ss = 0.0;
    const int pend = (part + 1) * 8192;
    for (int p = part * 8192 + t; p < pend; p += 256) {
        int b = p >> 14, q = p & 16383;
        int x = ((b * NCH + ch) << 14) + q;
        float v = ((qoff[x] + q1[x]) + q2[x]) + q3[x];
        qoff[x] = v;
        s += (double)v;
        ss += (double)v * (double)v;
    }
    __shared__ double sh1[256], sh2[256];
    sh1[t] = s; sh2[t] = ss;
    __syncthreads();
    for (int st = 128; st > 0; st >>= 1) {
        if (t < st) { sh1[t] += sh1[t + st]; sh2[t] += sh2[t + st]; }
        __syncthreads();
    }
    if (t == 0) {
        pstat[(ch * 8 + part) * 2] = sh1[0];
        pstat[(ch * 8 + part) * 2 + 1] = sh2[0];
    }
}

/* BN(stats inlined from pstat) + tanh + cum + floor -> gather row indices */
__global__ __launch_bounds__(128) void k_idx(const float* __restrict__ off,
                                             const double* __restrict__ pstat,
                                             const float* __restrict__ gamma,
                                             const float* __restrict__ beta,
                                             int* __restrict__ r2, int* __restrict__ r3) {
    int i = blockIdx.x, b = blockIdx.y, j = threadIdx.x;
    __shared__ float sm_mean[NCH], sm_rstd[NCH];
    if (j < NCH) {
        double s = 0.0, ss = 0.0;
        for (int kk = 0; kk < 8; ++kk) {
            s += pstat[(j * 8 + kk) * 2];
            ss += pstat[(j * 8 + kk) * 2 + 1];
        }
        double n = (double)(NB * NPIX);
        double m = s / n;
        double var = ss / n - m * m;
        sm_mean[j] = (float)m;
        sm_rstd[j] = (float)(1.0 / sqrt(var + 1e-5));
    }
    __syncthreads();
    float tt[NCH];
#pragma unroll
    for (int ch = 0; ch < NCH; ++ch) {
        float v = off[((b * NCH + ch) << 14) + (i << 7) + j];
        v = (v - sm_mean[ch]) * sm_rstd[ch];
        v = v * gamma[ch] + beta[ch];
        tt[ch] = (float)tanh((double)v);
    }
    float cz[9], cw[9];
    {
        const float* o = tt;
        cz[0] = 0.f;
        cz[1] = o[1];
        cz[2] = o[1] + o[2];
        cz[3] = (o[1] + o[2]) + o[3];
        cz[7] = o[7];
        cz[6] = o[7] + o[6];
        cz[5] = (o[7] + o[6]) + o[5];
        cz[4] = (cz[3] + cz[5]) * 0.5f;
        cz[8] = 0.f;
    }
    {
        const float* o = tt + 9;
        cw[0] = 0.f;
        cw[1] = o[1];
        cw[2] = o[1] + o[2];
        cw[3] = (o[1] + o[2]) + o[3];
        cw[7] = o[7];
        cw[6] = o[7] + o[6];
        cw[5] = (o[7] + o[6]) + o[5];
        cw[4] = (cw[3] + cw[5]) * 0.5f;
        cw[8] = 0.f;
    }
    const int rmax = NB * PADPIX - 1;
#pragma unroll
    for (int k = 0; k < 9; ++k) {
        int iy2 = (int)floorf((float)(i + 8 - k) + cz[k]);
        int ix2 = (int)floorf((float)(j + k) + cz[k]);
        int rr = b * 16384 + iy2 * HP + ix2;
        rr = rr < 0 ? 0 : (rr > rmax ? rmax : rr);
        r2[((b * 9 + k) << 14) + (i << 7) + j] = rr;
        int iy3 = (int)floorf((float)(i + k) + cw[k]);
        int ix3 = (int)floorf((float)(j + k) - cw[k]);
        int r3v = b * 16384 + iy3 * HP + ix3;
        r3v = r3v < 0 ? 0 : (r3v > rmax ? rmax : r3v);
        r3[((b * 9 + k) << 14) + (i << 7) + j] = r3v;
    }
}

/* main gathered strip-convs via MFMA bf16, double-buffered LDS (1 barrier/q),
   gather/W prefetched one q ahead, row indices two ahead; XCD-swizzled (b in
   low bits). MFMA accumulation order identical to r9. */
__global__ __launch_bounds__(256) void k_main(const unsigned short* __restrict__ fpf16,
                                              const int* __restrict__ r2,
                                              const int* __restrict__ r3,
                                              const unsigned short* __restrict__ wxb,
                                              const unsigned short* __restrict__ wyb,
                                              const float* __restrict__ bx,
                                              const float* __restrict__ by,
                                              float* __restrict__ out) {
    __shared__ __align__(16) unsigned short sAB[2 * 2 * 4608];  /* 36,864 B */

    const int id = blockIdx.x;
    const int b = id & 3, jt = (id >> 2) & 1, i = id >> 3;
    const int j0 = jt * 64;
    const int t = threadIdx.x;
    const int wv = t >> 6, lane = t & 63;
    const int m = lane & 15, quad = lane >> 4;
    const int sj = t >> 2, q4 = t & 3;
    const int bij = (i << 7) + j0 + sj;

    f32x4 acc[4];
#pragma unroll
    for (int ot = 0; ot < 4; ++ot) acc[ot] = (f32x4){0.f, 0.f, 0.f, 0.f};

    /* prefetch q=0 data + q=1 row index */
    int row0 = r2[((b * 9 + 0) << 14) + bij];
    const uint4* s0 = (const uint4*)(fpf16 + (size_t)row0 * 64 + q4 * 16);
    uint4 a0 = s0[0], a1 = s0[1];
    const uint4* ws0 = (const uint4*)(wxb + sj * 64 + q4 * 16);
    uint4 w0 = ws0[0], w1 = ws0[1];
    int idx_n = r2[((b * 9 + 1) << 14) + bij];

    for (int q = 0; q < 18; ++q) {
        unsigned short* cA = sAB + (q & 1) * (2 * 4608);
        unsigned short* cW = cA + 4608;
        *(uint4*)(cA + sj * 72 + q4 * 16) = a0;
        *(uint4*)(cA + sj * 72 + q4 * 16 + 8) = a1;
        *(uint4*)(cW + sj * 72 + q4 * 16) = w0;
        *(uint4*)(cW + sj * 72 + q4 * 16 + 8) = w1;
        __syncthreads();
        /* prefetch row index q+2 and data q+1 (overlaps this q's MFMA) */
        int idx_nn = 0;
        if (q + 2 < 18) {
            int k2 = (q + 2 < 9) ? q + 2 : q - 7;
            idx_nn = ((q + 2 < 9) ? r2 : r3)[((b * 9 + k2) << 14) + bij];
        }
        if (q + 1 < 18) {
            const uint4* sn = (const uint4*)(fpf16 + (size_t)idx_n * 64 + q4 * 16);
            a0 = sn[0]; a1 = sn[1];
            int k1 = (q + 1 < 9) ? q + 1 : q - 8;
            const uint4* wsn = (const uint4*)((((q + 1 < 9) ? wxb : wyb) + k1 * 4096)
                                              + sj * 64 + q4 * 16);
            w0 = wsn[0]; w1 = wsn[1];
        }
        bf16x8 fa0 = *(const bf16x8*)(cA + (wv * 16 + m) * 72 + quad * 8);
        bf16x8 fa1 = *(const bf16x8*)(cA + (wv * 16 + m) * 72 + 32 + quad * 8);
#pragma unroll
        for (int ot = 0; ot < 4; ++ot) {
            bf16x8 fb0 = *(const bf16x8*)(cW + (ot * 16 + m) * 72 + quad * 8);
            bf16x8 fb1 = *(const bf16x8*)(cW + (ot * 16 + m) * 72 + 32 + quad * 8);
            acc[ot] = __builtin_amdgcn_mfma_f32_16x16x32_bf16(fa0, fb0, acc[ot], 0, 0, 0);
            acc[ot] = __builtin_amdgcn_mfma_f32_16x16x32_bf16(fa1, fb1, acc[ot], 0, 0, 0);
        }
        idx_n = idx_nn;
    }
    __syncthreads();
    float* sD = (float*)sAB;    /* 64x68 floats = 17,408 B */
#pragma unroll
    for (int ot = 0; ot < 4; ++ot) {
        int o = ot * 16 + m;
        int jr = wv * 16 + quad * 4;
#pragma unroll
        for (int r = 0; r < 4; ++r)
            sD[o * 68 + jr + r] = acc[ot][r];
    }
    __syncthreads();
    {
        int o = t >> 2, jq = t & 3;
        float bias = bx[o] + by[o];
        float* dst = out + (((b * NO + o) << 7) + i) * NH + j0 + jq * 16;
        const float* srcrow = sD + o * 68 + jq * 16;
#pragma unroll
        for (int u = 0; u < 4; ++u) {
            float4 v = *(const float4*)(srcrow + u * 4);
            v.x += bias; v.y += bias; v.z += bias; v.w += bias;
            *(float4*)(dst + u * 4) = v;
        }
    }
}

extern "C" void kernel_launch(void* const* d_in, const int* in_sizes, int n_in,
                              void* d_out, int out_size, void* d_ws, size_t ws_size,
                              hipStream_t stream) {
    const float* f     = (const float*)d_in[0];
    const float* offw  = (const float*)d_in[1];
    const float* gamma = (const float*)d_in[3];
    const float* beta  = (const float*)d_in[4];
    const float* cwx   = (const float*)d_in[5];
    const float* cbx   = (const float*)d_in[6];
    const float* cwy   = (const float*)d_in[7];
    const float* cby   = (const float*)d_in[8];
    float* ws = (float*)d_ws;
    float* fpchw  = ws + O_FPCHW;
    unsigned short* fpf16 = (unsigned short*)(ws + O_FPF16);
    float* off    = ws + O_OFF;
    double* pstat = (double*)(ws + O_PST);
    unsigned short* wxb = (unsigned short*)(ws + O_WXB);
    unsigned short* wyb = (unsigned short*)(ws + O_WYB);
    float* pp1    = ws + O_PP1;
    float* pp2    = ws + O_PP2;
    float* pp3    = ws + O_PP3;
    float* wr     = ws + O_WR;
    int*   r2     = (int*)(ws + O_R2);
    int*   r3     = (int*)(ws + O_R3);
    float* out    = (float*)d_out;

    k_prep<<<NB_PREP, 256, 0, stream>>>(f, cwx, cwy, offw, fpchw, fpf16,
                                        wxb, wyb, wr);
    k_off<<<3072, 128, 0, stream>>>(fpchw, wr, off, pp1, pp2, pp3);
    k_stats1<<<dim3(NCH, 8), 256, 0, stream>>>(off, pp1, pp2, pp3, pstat);
    k_idx<<<dim3(NH, NB), 128, 0, stream>>>(off, pstat, gamma, beta, r2, r3);
    k_main<<<1024, 256, 0, stream>>>(fpf16, r2, r3, wxb, wyb, cbx, cby, out);
}